// Round 5
// baseline (18785.614 us; speedup 1.0000x reference)
//
#include <hip/hip_runtime.h>
#include <math.h>

#define T_ALL 200
#define G     2048
#define H     512
#define PW    132
#define PX    128

typedef __attribute__((address_space(1))) const unsigned int g_u32;
typedef __attribute__((address_space(3))) unsigned int l_u32;

// device-coherent (sc1) global->LDS async copy: reads the coherence point,
// bypassing possibly-stale per-XCD L2.
__device__ __forceinline__ void gl2lds16_coh(const void* g, void* l) {
    __builtin_amdgcn_global_load_lds((g_u32*)g, (l_u32*)l, 16, 0, 16);
}

__device__ __forceinline__ float sigf(float x) { return 1.0f / (1.0f + expf(-x)); }

// proposals [b][t][c] -> xT[t][c/4][b] (float4 over c)
__global__ __launch_bounds__(256) void transpose_x(const float4* __restrict__ in,
                                                   float4* __restrict__ out) {
    const int t = blockIdx.x;
    const int b = threadIdx.x;
    #pragma unroll 4
    for (int cc = 0; cc < 32; ++cc) {
        out[((size_t)t * 32 + cc) * 256 + b] = in[((size_t)b * 200 + t) * 32 + cc];
    }
}

// Tiled fp32 GEMM: xp[tloc][r][b] = bias[r] + sum_k W[r][k] * x[slot][k][b]
// x: [slot][K4][256] float4-over-k. Block tile 128r x 128b, thread tile 8x8.
__global__ __launch_bounds__(256, 2) void xproj_gemm(
    const float4* __restrict__ x, const float* __restrict__ W,
    const float* __restrict__ bih, const float* __restrict__ bhh,
    float* __restrict__ xp, int K4, int t0, int M)
{
    __shared__ float wl[2][32 * PW];
    __shared__ float xl[2][32 * PX];
    const int tloc = blockIdx.x;
    const int bg   = blockIdx.y;
    const int rc   = blockIdx.z;
    const int tid  = threadIdx.x;
    const int K    = K4 * 4;
    const int slot = (t0 + tloc) % M;
    const float4* xs = x + (size_t)slot * K4 * 256;
    const int rbase = rc * 128;
    const int bbase = bg * 128;

    const int bcol = tid & 15;
    const int rrow = tid >> 4;
    const int b0 = 4 * bcol, r0 = 4 * rrow;

    const int wr  = tid >> 3;
    const int wkq = tid & 7;
    const int xb  = tid & 127;
    const int xk4 = tid >> 7;

    float acc[8][8];
    #pragma unroll
    for (int i = 0; i < 8; ++i)
        #pragma unroll
        for (int j = 0; j < 8; ++j) acc[i][j] = 0.f;

    const int nk = K4 >> 3;
    float4 wreg[4], xreg[4];

    #pragma unroll
    for (int j = 0; j < 4; ++j) {
        wreg[j] = *(const float4*)(W + (size_t)(rbase + wr + 32 * j) * K + wkq * 4);
        xreg[j] = xs[(size_t)(xk4 + 2 * j) * 256 + bbase + xb];
    }
    #pragma unroll
    for (int j = 0; j < 4; ++j) {
        #pragma unroll
        for (int i = 0; i < 4; ++i) {
            wl[0][(wkq * 4 + i) * PW + wr + 32 * j] = ((const float*)&wreg[j])[i];
            xl[0][((xk4 + 2 * j) * 4 + i) * PX + xb] = ((const float*)&xreg[j])[i];
        }
    }
    __syncthreads();

    for (int ro = 0; ro < nk; ++ro) {
        if (ro + 1 < nk) {
            const int k0 = (ro + 1) * 32;
            #pragma unroll
            for (int j = 0; j < 4; ++j) {
                wreg[j] = *(const float4*)(W + (size_t)(rbase + wr + 32 * j) * K + k0 + wkq * 4);
                xreg[j] = xs[(size_t)(k0 / 4 + xk4 + 2 * j) * 256 + bbase + xb];
            }
        }
        const float* wlb = wl[ro & 1];
        const float* xlb = xl[ro & 1];
        #pragma unroll 2
        for (int k = 0; k < 32; ++k) {
            const float4 w0 = *(const float4*)&wlb[k * PW + r0];
            const float4 w1 = *(const float4*)&wlb[k * PW + r0 + 64];
            const float4 v0 = *(const float4*)&xlb[k * PX + b0];
            const float4 v1 = *(const float4*)&xlb[k * PX + b0 + 64];
            const float wf[8] = {w0.x, w0.y, w0.z, w0.w, w1.x, w1.y, w1.z, w1.w};
            const float xf[8] = {v0.x, v0.y, v0.z, v0.w, v1.x, v1.y, v1.z, v1.w};
            #pragma unroll
            for (int i = 0; i < 8; ++i)
                #pragma unroll
                for (int j = 0; j < 8; ++j)
                    acc[i][j] += wf[i] * xf[j];
        }
        __syncthreads();
        if (ro + 1 < nk) {
            const int nb = (ro + 1) & 1;
            #pragma unroll
            for (int j = 0; j < 4; ++j) {
                #pragma unroll
                for (int i = 0; i < 4; ++i) {
                    wl[nb][(wkq * 4 + i) * PW + wr + 32 * j] = ((const float*)&wreg[j])[i];
                    xl[nb][((xk4 + 2 * j) * 4 + i) * PX + xb] = ((const float*)&xreg[j])[i];
                }
            }
            __syncthreads();
        }
    }

    #pragma unroll
    for (int ii = 0; ii < 8; ++ii) {
        const int rl = (ii < 4) ? (r0 + ii) : (r0 + 60 + ii);
        const int gr = rbase + rl;
        const float bias = bih[gr] + bhh[gr];
        float* o = xp + ((size_t)tloc * G + gr) * 256 + bbase;
        float4 u0 = {acc[ii][0] + bias, acc[ii][1] + bias, acc[ii][2] + bias, acc[ii][3] + bias};
        float4 u1 = {acc[ii][4] + bias, acc[ii][5] + bias, acc[ii][6] + bias, acc[ii][7] + bias};
        *(float4*)(o + b0) = u0;
        *(float4*)(o + b0 + 64) = u1;
    }
}

// Fused two-layer LSTM scan, software-pipelined across layers.
// Superstep t: layer0 computes h0[t] (t<200), layer1 computes h1[t-1] (t>=1).
// h0/h1 are 2-slot ping-pongs (slot = step parity). grid (64 hidgrp, 4 bgrp),
// block 256 = 4 waves; thread owns 2 hids x 4 gates per layer (16 accumulators).
// Barrier: one fresh cache line per (superstep, bgroup); arrive = no-return
// relaxed agent atomicAdd; tid0 spins with s_sleep; no cache invalidates.
__global__ __launch_bounds__(256) void lstm_fused(
    const float* __restrict__ xp0, const float* __restrict__ Whh0,
    const float* __restrict__ Wih1, const float* __restrict__ Whh1,
    const float* __restrict__ bih1, const float* __restrict__ bhh1,
    float4* __restrict__ h0buf, float4* __restrict__ h1buf,
    float* __restrict__ cb0, float* __restrict__ cb1,
    int t0, int t1, int* __restrict__ arr)
{
    __shared__ float4 hs[2][2048];   // 2 x 32 KB double buffer
    const int tid  = threadIdx.x;
    const int wv   = tid >> 6;
    const int lane = tid & 63;
    const int bi   = blockIdx.x;     // 0..63 hid group
    const int bg   = blockIdx.y;     // 0..3 batch group
    const int bG   = bg * 64 + lane;
    const int hid0 = __builtin_amdgcn_readfirstlane(bi * 8 + wv * 2);

    const float *w0[8], *wi[8], *w1[8];
    float bs1[8];
    #pragma unroll
    for (int p = 0; p < 2; ++p)
        #pragma unroll
        for (int q = 0; q < 4; ++q) {
            const int idx = p * 4 + q;
            const int r = q * H + hid0 + p;
            w0[idx] = Whh0 + (size_t)r * H;
            wi[idx] = Wih1 + (size_t)r * H;
            w1[idx] = Whh1 + (size_t)r * H;
            bs1[idx] = bih1[r] + bhh1[r];
        }

    float c00, c01, c10, c11;
    if (t0 > 0) {
        c00 = cb0[(size_t)hid0 * 256 + bG];
        c01 = cb0[(size_t)(hid0 + 1) * 256 + bG];
        c10 = cb1[(size_t)hid0 * 256 + bG];
        c11 = cb1[(size_t)(hid0 + 1) * 256 + bG];
    } else { c00 = c01 = c10 = c11 = 0.f; }

    float a0[8];
    if (t0 < T_ALL) {
        #pragma unroll
        for (int p = 0; p < 2; ++p)
            #pragma unroll
            for (int q = 0; q < 4; ++q)
                a0[p * 4 + q] = xp0[(size_t)(q * H + hid0 + p) * 256 + bG];
    } else {
        #pragma unroll
        for (int i = 0; i < 8; ++i) a0[i] = 0.f;
    }

    for (int t = t0; t < t1; ++t) {
        float a1[8];
        #pragma unroll
        for (int i = 0; i < 8; ++i) a1[i] = bs1[i];

        if (t >= 1) {
            const float4* hin0 = h0buf + (size_t)((t - 1) & 1) * 32768;
            const float4* hin1 = h1buf + (size_t)((t - 2) & 1) * 32768;
            const int nro = (t >= 2) ? 8 : 4;
            #pragma unroll
            for (int j = 0; j < 8; ++j) {
                const int kk = wv + 4 * j;
                gl2lds16_coh(hin0 + (size_t)kk * 256 + bG, &hs[0][kk * 64]);
            }
            __syncthreads();
            for (int ro = 0; ro < nro; ++ro) {
                if (ro + 1 < nro) {
                    const float4* src = (ro + 1 < 4)
                        ? hin0 + (size_t)((ro + 1) * 32) * 256
                        : hin1 + (size_t)((ro - 3) * 32) * 256;
                    #pragma unroll
                    for (int j = 0; j < 8; ++j) {
                        const int kk = wv + 4 * j;
                        gl2lds16_coh(src + (size_t)kk * 256 + bG, &hs[(ro + 1) & 1][kk * 64]);
                    }
                }
                const float4* hb = hs[ro & 1];
                if (ro < 4) {
                    const int kb = ro * 128;
                    #pragma unroll 2
                    for (int kk = 0; kk < 32; ++kk) {
                        const float4 v = hb[kk * 64 + lane];
                        const int ko = kb + kk * 4;
                        #pragma unroll
                        for (int i = 0; i < 8; ++i) {
                            const float4 w = *(const float4*)(w0[i] + ko);
                            a0[i] += w.x*v.x + w.y*v.y + w.z*v.z + w.w*v.w;
                            const float4 u = *(const float4*)(wi[i] + ko);
                            a1[i] += u.x*v.x + u.y*v.y + u.z*v.z + u.w*v.w;
                        }
                    }
                } else {
                    const int kb = (ro - 4) * 128;
                    #pragma unroll 2
                    for (int kk = 0; kk < 32; ++kk) {
                        const float4 v = hb[kk * 64 + lane];
                        const int ko = kb + kk * 4;
                        #pragma unroll
                        for (int i = 0; i < 8; ++i) {
                            const float4 w = *(const float4*)(w1[i] + ko);
                            a1[i] += w.x*v.x + w.y*v.y + w.z*v.z + w.w*v.w;
                        }
                    }
                }
                __syncthreads();
            }
        }

        // prefetch next superstep's xp0 (independent of h) before the barrier
        float an[8];
        const bool pf = (t + 1 < t1) && (t + 1 < T_ALL);
        if (pf) {
            const float* xpt = xp0 + (size_t)(t + 1 - t0) * G * 256;
            #pragma unroll
            for (int p = 0; p < 2; ++p)
                #pragma unroll
                for (int q = 0; q < 4; ++q)
                    an[p * 4 + q] = xpt[(size_t)(q * H + hid0 + p) * 256 + bG];
        } else {
            #pragma unroll
            for (int i = 0; i < 8; ++i) an[i] = 0.f;
        }

        if (t < T_ALL) {
            float* hw = (float*)(h0buf + (size_t)(t & 1) * 32768);
            {
                const float ig = sigf(a0[0]), fg = sigf(a0[1]);
                const float gg = tanhf(a0[2]), og = sigf(a0[3]);
                c00 = fg * c00 + ig * gg;
                const float hv = og * tanhf(c00);
                __hip_atomic_store(&hw[(((hid0 >> 2) * 256) + bG) * 4 + (hid0 & 3)], hv,
                                   __ATOMIC_RELAXED, __HIP_MEMORY_SCOPE_AGENT);
            }
            {
                const float ig = sigf(a0[4]), fg = sigf(a0[5]);
                const float gg = tanhf(a0[6]), og = sigf(a0[7]);
                c01 = fg * c01 + ig * gg;
                const float hv = og * tanhf(c01);
                const int hh = hid0 + 1;
                __hip_atomic_store(&hw[(((hh >> 2) * 256) + bG) * 4 + (hh & 3)], hv,
                                   __ATOMIC_RELAXED, __HIP_MEMORY_SCOPE_AGENT);
            }
        }
        if (t >= 1) {
            float* hw = (float*)(h1buf + (size_t)((t - 1) & 1) * 32768);
            {
                const float ig = sigf(a1[0]), fg = sigf(a1[1]);
                const float gg = tanhf(a1[2]), og = sigf(a1[3]);
                c10 = fg * c10 + ig * gg;
                const float hv = og * tanhf(c10);
                __hip_atomic_store(&hw[(((hid0 >> 2) * 256) + bG) * 4 + (hid0 & 3)], hv,
                                   __ATOMIC_RELAXED, __HIP_MEMORY_SCOPE_AGENT);
            }
            {
                const float ig = sigf(a1[4]), fg = sigf(a1[5]);
                const float gg = tanhf(a1[6]), og = sigf(a1[7]);
                c11 = fg * c11 + ig * gg;
                const float hv = og * tanhf(c11);
                const int hh = hid0 + 1;
                __hip_atomic_store(&hw[(((hh >> 2) * 256) + bG) * 4 + (hh & 3)], hv,
                                   __ATOMIC_RELAXED, __HIP_MEMORY_SCOPE_AGENT);
            }
        }

        if (t + 1 < t1) {
            __threadfence_block();       // waitcnt drain only
            __syncthreads();             // all h stores of this block complete
            int* cp = arr + ((size_t)t * 4 + bg) * 32;   // fresh line per step+group
            if (tid == 0) {
                __hip_atomic_fetch_add(cp, 1, __ATOMIC_RELAXED, __HIP_MEMORY_SCOPE_AGENT);
                while (__hip_atomic_load(cp, __ATOMIC_RELAXED, __HIP_MEMORY_SCOPE_AGENT) < 64)
                    __builtin_amdgcn_s_sleep(1);
            }
            __syncthreads();
        }

        #pragma unroll
        for (int i = 0; i < 8; ++i) a0[i] = an[i];
    }

    cb0[(size_t)hid0 * 256 + bG] = c00;
    cb0[(size_t)(hid0 + 1) * 256 + bG] = c01;
    cb1[(size_t)hid0 * 256 + bG] = c10;
    cb1[(size_t)(hid0 + 1) * 256 + bG] = c11;
}

// heads: base[k/4][b][4k] -> cls (256x40), bbox (256x2), 2 zero scalars
__global__ __launch_bounds__(64) void heads(
    const float4* __restrict__ base, const float4* __restrict__ clsW,
    const float* __restrict__ clsb, const float4* __restrict__ bbW,
    const float* __restrict__ bbb, float* __restrict__ out)
{
    const int b = blockIdx.x;
    const int j = threadIdx.x;
    if (j < 42) {
        const float4* w = (j < 40) ? (clsW + (size_t)j * 128) : (bbW + (size_t)(j - 40) * 128);
        float acc = 0.f;
        #pragma unroll 4
        for (int kk = 0; kk < 128; ++kk) {
            const float4 bv = base[(size_t)kk * 256 + b];
            const float4 wv = w[kk];
            acc += bv.x*wv.x + bv.y*wv.y + bv.z*wv.z + bv.w*wv.w;
        }
        if (j < 40) out[(size_t)b * 40 + j] = acc + clsb[j];
        else        out[10240 + (size_t)b * 2 + (j - 40)] = acc + bbb[j - 40];
    }
    if (b == 0 && (j == 62 || j == 63)) out[10752 + (j - 62)] = 0.f;
}

extern "C" void kernel_launch(void* const* d_in, const int* in_sizes, int n_in,
                              void* d_out, int out_size, void* d_ws, size_t ws_size,
                              hipStream_t stream) {
    const float* proposals = (const float*)d_in[2];
    const float* Wih0 = (const float*)d_in[4];
    const float* Whh0 = (const float*)d_in[5];
    const float* bih0 = (const float*)d_in[6];
    const float* bhh0 = (const float*)d_in[7];
    const float* Wih1 = (const float*)d_in[8];
    const float* Whh1 = (const float*)d_in[9];
    const float* bih1 = (const float*)d_in[10];
    const float* bhh1 = (const float*)d_in[11];
    const float* clsW = (const float*)d_in[12];
    const float* clsb = (const float*)d_in[13];
    const float* bbW  = (const float*)d_in[14];
    const float* bbb  = (const float*)d_in[15];

    char* ws = (char*)d_ws;
    const size_t XT_B  = 200ull * 32 * 256 * 16;   // 26,214,400
    const size_t HB_B  = 2ull * 32768 * 16;        // 1,048,576 per layer ping-pong
    const size_t C_B   = 512ull * 256 * 4;         // 524,288 per layer
    const size_t ARR_B = 201ull * 4 * 128;         // fresh line per (step, bgroup)
    const size_t XP_T  = (size_t)G * 256 * 4;      // 2,097,152 per layer0 step
    const size_t base  = XT_B + 2 * HB_B + 2 * C_B + ARR_B;

    long long avail = (long long)ws_size - (long long)base;
    int TC = avail > 0 ? (int)(avail / (long long)XP_T) : 1;
    if (TC > T_ALL + 1) TC = T_ALL + 1;
    if (TC < 1) TC = 1;

    float4* xT  = (float4*)ws;
    float4* h0b = (float4*)(ws + XT_B);
    float4* h1b = (float4*)(ws + XT_B + HB_B);
    float*  cb0 = (float*)(ws + XT_B + 2 * HB_B);
    float*  cb1 = (float*)(ws + XT_B + 2 * HB_B + C_B);
    int*    arr = (int*)(ws + XT_B + 2 * HB_B + 2 * C_B);
    float*  xp0 = (float*)(ws + base);

    hipMemsetAsync(arr, 0, ARR_B, stream);

    transpose_x<<<200, 256, 0, stream>>>((const float4*)proposals, xT);

    for (int t0 = 0; t0 < T_ALL + 1; t0 += TC) {
        const int t1 = (t0 + TC < T_ALL + 1) ? (t0 + TC) : (T_ALL + 1);
        const int lim = (t1 < T_ALL) ? t1 : T_ALL;
        const int len0 = lim - t0;                 // layer0 steps in this chunk
        if (len0 > 0)
            xproj_gemm<<<dim3(len0, 2, 16), 256, 0, stream>>>(xT, Wih0, bih0, bhh0,
                                                              xp0, 32, t0, 1 << 30);
        lstm_fused<<<dim3(64, 4), 256, 0, stream>>>(xp0, Whh0, Wih1, Whh1, bih1, bhh1,
                                                    h0b, h1b, cb0, cb1, t0, t1, arr);
    }

    // base_feat = h1 slot (199 & 1) = 1
    heads<<<256, 64, 0, stream>>>((const float4*)(h1b + 32768), (const float4*)clsW,
                                  clsb, (const float4*)bbW, bbb, (float*)d_out);
}

// Round 6
// 12801.370 us; speedup vs baseline: 1.4675x; 1.4675x over previous
//
#include <hip/hip_runtime.h>
#include <math.h>

#define T_ALL 200
#define G     2048
#define H     512
#define PW    132
#define PX    128

typedef __attribute__((address_space(1))) const unsigned int g_u32;
typedef __attribute__((address_space(3))) unsigned int l_u32;

// device-coherent (sc1) global->LDS async copy: reads the coherence point,
// bypassing possibly-stale per-XCD L2.
__device__ __forceinline__ void gl2lds16_coh(const void* g, void* l) {
    __builtin_amdgcn_global_load_lds((g_u32*)g, (l_u32*)l, 16, 0, 16);
}

__device__ __forceinline__ float sigf(float x) { return 1.0f / (1.0f + expf(-x)); }

// proposals [b][t][c] -> xT[t][c/4][b] (float4 over c)
__global__ __launch_bounds__(256) void transpose_x(const float4* __restrict__ in,
                                                   float4* __restrict__ out) {
    const int t = blockIdx.x;
    const int b = threadIdx.x;
    #pragma unroll 4
    for (int cc = 0; cc < 32; ++cc) {
        out[((size_t)t * 32 + cc) * 256 + b] = in[((size_t)b * 200 + t) * 32 + cc];
    }
}

// Tiled fp32 GEMM: xp[tloc][r][b] = bias[r] + sum_k W[r][k] * x[t][k][b]
__global__ __launch_bounds__(256, 2) void xproj_gemm(
    const float4* __restrict__ x, const float* __restrict__ W,
    const float* __restrict__ bih, const float* __restrict__ bhh,
    float* __restrict__ xp, int K4, int t0)
{
    __shared__ float wl[2][32 * PW];
    __shared__ float xl[2][32 * PX];
    const int tloc = blockIdx.x;
    const int bg   = blockIdx.y;
    const int rc   = blockIdx.z;
    const int tid  = threadIdx.x;
    const int K    = K4 * 4;
    const float4* xs = x + (size_t)(t0 + tloc) * K4 * 256;
    const int rbase = rc * 128;
    const int bbase = bg * 128;

    const int bcol = tid & 15;
    const int rrow = tid >> 4;
    const int b0 = 4 * bcol, r0 = 4 * rrow;

    const int wr  = tid >> 3;
    const int wkq = tid & 7;
    const int xb  = tid & 127;
    const int xk4 = tid >> 7;

    float acc[8][8];
    #pragma unroll
    for (int i = 0; i < 8; ++i)
        #pragma unroll
        for (int j = 0; j < 8; ++j) acc[i][j] = 0.f;

    const int nk = K4 >> 3;
    float4 wreg[4], xreg[4];

    #pragma unroll
    for (int j = 0; j < 4; ++j) {
        wreg[j] = *(const float4*)(W + (size_t)(rbase + wr + 32 * j) * K + wkq * 4);
        xreg[j] = xs[(size_t)(xk4 + 2 * j) * 256 + bbase + xb];
    }
    #pragma unroll
    for (int j = 0; j < 4; ++j) {
        #pragma unroll
        for (int i = 0; i < 4; ++i) {
            wl[0][(wkq * 4 + i) * PW + wr + 32 * j] = ((const float*)&wreg[j])[i];
            xl[0][((xk4 + 2 * j) * 4 + i) * PX + xb] = ((const float*)&xreg[j])[i];
        }
    }
    __syncthreads();

    for (int ro = 0; ro < nk; ++ro) {
        if (ro + 1 < nk) {
            const int k0 = (ro + 1) * 32;
            #pragma unroll
            for (int j = 0; j < 4; ++j) {
                wreg[j] = *(const float4*)(W + (size_t)(rbase + wr + 32 * j) * K + k0 + wkq * 4);
                xreg[j] = xs[(size_t)(k0 / 4 + xk4 + 2 * j) * 256 + bbase + xb];
            }
        }
        const float* wlb = wl[ro & 1];
        const float* xlb = xl[ro & 1];
        #pragma unroll 2
        for (int k = 0; k < 32; ++k) {
            const float4 w0 = *(const float4*)&wlb[k * PW + r0];
            const float4 w1 = *(const float4*)&wlb[k * PW + r0 + 64];
            const float4 v0 = *(const float4*)&xlb[k * PX + b0];
            const float4 v1 = *(const float4*)&xlb[k * PX + b0 + 64];
            const float wf[8] = {w0.x, w0.y, w0.z, w0.w, w1.x, w1.y, w1.z, w1.w};
            const float xf[8] = {v0.x, v0.y, v0.z, v0.w, v1.x, v1.y, v1.z, v1.w};
            #pragma unroll
            for (int i = 0; i < 8; ++i)
                #pragma unroll
                for (int j = 0; j < 8; ++j)
                    acc[i][j] += wf[i] * xf[j];
        }
        __syncthreads();
        if (ro + 1 < nk) {
            const int nb = (ro + 1) & 1;
            #pragma unroll
            for (int j = 0; j < 4; ++j) {
                #pragma unroll
                for (int i = 0; i < 4; ++i) {
                    wl[nb][(wkq * 4 + i) * PW + wr + 32 * j] = ((const float*)&wreg[j])[i];
                    xl[nb][((xk4 + 2 * j) * 4 + i) * PX + xb] = ((const float*)&xreg[j])[i];
                }
            }
            __syncthreads();
        }
    }

    #pragma unroll
    for (int ii = 0; ii < 8; ++ii) {
        const int rl = (ii < 4) ? (r0 + ii) : (r0 + 60 + ii);
        const int gr = rbase + rl;
        const float bias = bih[gr] + bhh[gr];
        float* o = xp + ((size_t)tloc * G + gr) * 256 + bbase;
        float4 u0 = {acc[ii][0] + bias, acc[ii][1] + bias, acc[ii][2] + bias, acc[ii][3] + bias};
        float4 u1 = {acc[ii][4] + bias, acc[ii][5] + bias, acc[ii][6] + bias, acc[ii][7] + bias};
        *(float4*)(o + b0) = u0;
        *(float4*)(o + b0 + 64) = u1;
    }
}

// Fused two-layer LSTM scan. 256 blocks x 512 threads (8 waves = 2/SIMD).
// XCD-clustered mapping: XCD = blockIdx%8 hosts 8 hid-groups x 4 b-groups ->
// per-XCD weight working set ~1.6 MB (fits 4 MB L2, stays resident all steps).
// Thread owns 1 hid (wave-uniform -> scalar weight loads) x 1 batch, both layers.
// Superstep t: layer0 -> h0[t] (t<200), layer1 -> h1[t-1] (t>=1). h ping-pong
// via sc1 stores / sc1 gl2lds. Barrier: fresh line per (step,bgroup).
__global__ __launch_bounds__(512) void lstm_fused(
    const float* __restrict__ xp0, const float* __restrict__ Whh0,
    const float* __restrict__ Wih1, const float* __restrict__ Whh1,
    const float* __restrict__ bih1, const float* __restrict__ bhh1,
    float4* __restrict__ h0buf, float4* __restrict__ h1buf,
    float* __restrict__ cb0, float* __restrict__ cb1,
    int t0, int t1, int* __restrict__ arr)
{
    __shared__ float4 hs[2][2048];   // 2 x 32 KB double buffer
    const int tid  = threadIdx.x;
    const int wv   = tid >> 6;       // 0..7
    const int lane = tid & 63;
    const int f    = blockIdx.x;     // 0..255
    const int xcd  = f & 7;
    const int jj   = f >> 3;         // 0..31
    const int bg   = jj & 3;         // batch group (64 batches)
    const int hg   = xcd + 8 * (jj >> 2);   // hid group 0..63, clustered per XCD
    const int bG   = bg * 64 + lane;
    const int hid  = __builtin_amdgcn_readfirstlane(hg * 8 + wv);

    const float *w0[4], *wi[4], *w1[4];
    float bs1[4];
    #pragma unroll
    for (int q = 0; q < 4; ++q) {
        const int r = q * H + hid;
        w0[q] = Whh0 + (size_t)r * H;
        wi[q] = Wih1 + (size_t)r * H;
        w1[q] = Whh1 + (size_t)r * H;
        bs1[q] = bih1[r] + bhh1[r];
    }

    float c0, c1;
    if (t0 > 0) {
        c0 = cb0[(size_t)hid * 256 + bG];
        c1 = cb1[(size_t)hid * 256 + bG];
    } else { c0 = 0.f; c1 = 0.f; }

    float a0[4];
    if (t0 < T_ALL) {
        #pragma unroll
        for (int q = 0; q < 4; ++q)
            a0[q] = xp0[(size_t)(q * H + hid) * 256 + bG];
    } else {
        #pragma unroll
        for (int q = 0; q < 4; ++q) a0[q] = 0.f;
    }

    for (int t = t0; t < t1; ++t) {
        float a1[4];
        #pragma unroll
        for (int q = 0; q < 4; ++q) a1[q] = bs1[q];

        if (t >= 1) {
            const float4* hin0 = h0buf + (size_t)((t - 1) & 1) * 32768;
            const float4* hin1 = h1buf + (size_t)((t - 2) & 1) * 32768;
            const int nro = (t >= 2) ? 8 : 4;
            // stage chunk 0 (32 k4-rows x 64 batches = 32 KB)
            #pragma unroll
            for (int s = 0; s < 4; ++s) {
                const int kk = wv + 8 * s;
                gl2lds16_coh(hin0 + (size_t)kk * 256 + bG, &hs[0][kk * 64]);
            }
            __syncthreads();
            for (int ro = 0; ro < nro; ++ro) {
                if (ro + 1 < nro) {
                    const float4* src = (ro + 1 < 4)
                        ? hin0 + (size_t)((ro + 1) * 32) * 256
                        : hin1 + (size_t)((ro - 3) * 32) * 256;
                    #pragma unroll
                    for (int s = 0; s < 4; ++s) {
                        const int kk = wv + 8 * s;
                        gl2lds16_coh(src + (size_t)kk * 256 + bG, &hs[(ro + 1) & 1][kk * 64]);
                    }
                }
                const float4* hb = hs[ro & 1];
                if (ro < 4) {
                    const int kb = ro * 128;
                    #pragma unroll 4
                    for (int kk = 0; kk < 32; ++kk) {
                        const float4 v = hb[kk * 64 + lane];
                        const int ko = kb + kk * 4;
                        #pragma unroll
                        for (int q = 0; q < 4; ++q) {
                            const float4 w = *(const float4*)(w0[q] + ko);
                            a0[q] += w.x*v.x + w.y*v.y + w.z*v.z + w.w*v.w;
                            const float4 u = *(const float4*)(wi[q] + ko);
                            a1[q] += u.x*v.x + u.y*v.y + u.z*v.z + u.w*v.w;
                        }
                    }
                } else {
                    const int kb = (ro - 4) * 128;
                    #pragma unroll 4
                    for (int kk = 0; kk < 32; ++kk) {
                        const float4 v = hb[kk * 64 + lane];
                        const int ko = kb + kk * 4;
                        #pragma unroll
                        for (int q = 0; q < 4; ++q) {
                            const float4 w = *(const float4*)(w1[q] + ko);
                            a1[q] += w.x*v.x + w.y*v.y + w.z*v.z + w.w*v.w;
                        }
                    }
                }
                __syncthreads();
            }
        }

        // prefetch next superstep's xp0 before the barrier
        float an[4];
        const bool pf = (t + 1 < t1) && (t + 1 < T_ALL);
        if (pf) {
            const float* xpt = xp0 + (size_t)(t + 1 - t0) * G * 256;
            #pragma unroll
            for (int q = 0; q < 4; ++q)
                an[q] = xpt[(size_t)(q * H + hid) * 256 + bG];
        } else {
            #pragma unroll
            for (int q = 0; q < 4; ++q) an[q] = 0.f;
        }

        if (t < T_ALL) {
            float* hw = (float*)(h0buf + (size_t)(t & 1) * 32768);
            const float ig = sigf(a0[0]), fg = sigf(a0[1]);
            const float gg = tanhf(a0[2]), og = sigf(a0[3]);
            c0 = fg * c0 + ig * gg;
            const float hv = og * tanhf(c0);
            __hip_atomic_store(&hw[(((hid >> 2) * 256) + bG) * 4 + (hid & 3)], hv,
                               __ATOMIC_RELAXED, __HIP_MEMORY_SCOPE_AGENT);
        }
        if (t >= 1) {
            float* hw = (float*)(h1buf + (size_t)((t - 1) & 1) * 32768);
            const float ig = sigf(a1[0]), fg = sigf(a1[1]);
            const float gg = tanhf(a1[2]), og = sigf(a1[3]);
            c1 = fg * c1 + ig * gg;
            const float hv = og * tanhf(c1);
            __hip_atomic_store(&hw[(((hid >> 2) * 256) + bG) * 4 + (hid & 3)], hv,
                               __ATOMIC_RELAXED, __HIP_MEMORY_SCOPE_AGENT);
        }

        if (t + 1 < t1) {
            __threadfence_block();       // drain stores (waitcnt only)
            __syncthreads();
            int* cp = arr + ((size_t)t * 4 + bg) * 32;   // fresh line per step+group
            if (tid == 0) {
                __hip_atomic_fetch_add(cp, 1, __ATOMIC_RELAXED, __HIP_MEMORY_SCOPE_AGENT);
                while (__hip_atomic_load(cp, __ATOMIC_RELAXED, __HIP_MEMORY_SCOPE_AGENT) < 64)
                    __builtin_amdgcn_s_sleep(1);
            }
            __syncthreads();
        }

        #pragma unroll
        for (int q = 0; q < 4; ++q) a0[q] = an[q];
    }

    cb0[(size_t)hid * 256 + bG] = c0;
    cb1[(size_t)hid * 256 + bG] = c1;
}

// heads: base[k/4][b][4k] -> cls (256x40), bbox (256x2), 2 zero scalars
__global__ __launch_bounds__(64) void heads(
    const float4* __restrict__ base, const float4* __restrict__ clsW,
    const float* __restrict__ clsb, const float4* __restrict__ bbW,
    const float* __restrict__ bbb, float* __restrict__ out)
{
    const int b = blockIdx.x;
    const int j = threadIdx.x;
    if (j < 42) {
        const float4* w = (j < 40) ? (clsW + (size_t)j * 128) : (bbW + (size_t)(j - 40) * 128);
        float acc = 0.f;
        #pragma unroll 4
        for (int kk = 0; kk < 128; ++kk) {
            const float4 bv = base[(size_t)kk * 256 + b];
            const float4 wv = w[kk];
            acc += bv.x*wv.x + bv.y*wv.y + bv.z*wv.z + bv.w*wv.w;
        }
        if (j < 40) out[(size_t)b * 40 + j] = acc + clsb[j];
        else        out[10240 + (size_t)b * 2 + (j - 40)] = acc + bbb[j - 40];
    }
    if (b == 0 && (j == 62 || j == 63)) out[10752 + (j - 62)] = 0.f;
}

extern "C" void kernel_launch(void* const* d_in, const int* in_sizes, int n_in,
                              void* d_out, int out_size, void* d_ws, size_t ws_size,
                              hipStream_t stream) {
    const float* proposals = (const float*)d_in[2];
    const float* Wih0 = (const float*)d_in[4];
    const float* Whh0 = (const float*)d_in[5];
    const float* bih0 = (const float*)d_in[6];
    const float* bhh0 = (const float*)d_in[7];
    const float* Wih1 = (const float*)d_in[8];
    const float* Whh1 = (const float*)d_in[9];
    const float* bih1 = (const float*)d_in[10];
    const float* bhh1 = (const float*)d_in[11];
    const float* clsW = (const float*)d_in[12];
    const float* clsb = (const float*)d_in[13];
    const float* bbW  = (const float*)d_in[14];
    const float* bbb  = (const float*)d_in[15];

    char* ws = (char*)d_ws;
    const size_t XT_B  = 200ull * 32 * 256 * 16;   // 26,214,400
    const size_t HB_B  = 2ull * 32768 * 16;        // 1,048,576 per layer ping-pong
    const size_t C_B   = 512ull * 256 * 4;         // 524,288 per layer
    const size_t ARR_B = 201ull * 4 * 128;         // fresh line per (step, bgroup)
    const size_t XP_T  = (size_t)G * 256 * 4;      // 2,097,152 per layer0 step
    const size_t base  = XT_B + 2 * HB_B + 2 * C_B + ARR_B;

    long long avail = (long long)ws_size - (long long)base;
    int TC = avail > 0 ? (int)(avail / (long long)XP_T) : 1;
    if (TC > T_ALL + 1) TC = T_ALL + 1;
    if (TC < 1) TC = 1;

    float4* xT  = (float4*)ws;
    float4* h0b = (float4*)(ws + XT_B);
    float4* h1b = (float4*)(ws + XT_B + HB_B);
    float*  cb0 = (float*)(ws + XT_B + 2 * HB_B);
    float*  cb1 = (float*)(ws + XT_B + 2 * HB_B + C_B);
    int*    arr = (int*)(ws + XT_B + 2 * HB_B + 2 * C_B);
    float*  xp0 = (float*)(ws + base);

    hipMemsetAsync(arr, 0, ARR_B, stream);

    transpose_x<<<200, 256, 0, stream>>>((const float4*)proposals, xT);

    for (int t0 = 0; t0 < T_ALL + 1; t0 += TC) {
        const int t1 = (t0 + TC < T_ALL + 1) ? (t0 + TC) : (T_ALL + 1);
        const int lim = (t1 < T_ALL) ? t1 : T_ALL;
        const int len0 = lim - t0;
        if (len0 > 0)
            xproj_gemm<<<dim3(len0, 2, 16), 256, 0, stream>>>(xT, Wih0, bih0, bhh0,
                                                              xp0, 32, t0);
        lstm_fused<<<dim3(256), 512, 0, stream>>>(xp0, Whh0, Wih1, Whh1, bih1, bhh1,
                                                  h0b, h1b, cb0, cb1, t0, t1, arr);
    }

    // base_feat = h1 slot (199 & 1) = 1
    heads<<<256, 64, 0, stream>>>((const float4*)(h1b + 32768), (const float4*)clsW,
                                  clsb, (const float4*)bbW, bbb, (float*)d_out);
}

// Round 7
// 11869.276 us; speedup vs baseline: 1.5827x; 1.0785x over previous
//
#include <hip/hip_runtime.h>
#include <math.h>

#define T_ALL 200
#define G     2048
#define H     512
#define PW    132
#define PX    128

typedef __attribute__((address_space(1))) const unsigned int g_u32;
typedef __attribute__((address_space(3))) unsigned int l_u32;

__device__ __forceinline__ void gl2lds16(const void* g, void* l) {
    __builtin_amdgcn_global_load_lds((g_u32*)g, (l_u32*)l, 16, 0, 0);
}

__device__ __forceinline__ float sigf(float x) { return 1.0f / (1.0f + expf(-x)); }

// proposals [b][t][c] -> xT[t][c/4][b] (float4 over c)
__global__ __launch_bounds__(256) void transpose_x(const float4* __restrict__ in,
                                                   float4* __restrict__ out) {
    const int t = blockIdx.x;
    const int b = threadIdx.x;
    #pragma unroll 4
    for (int cc = 0; cc < 32; ++cc) {
        out[((size_t)t * 32 + cc) * 256 + b] = in[((size_t)b * 200 + t) * 32 + cc];
    }
}

// Tiled fp32 GEMM: xp[tloc][r][b] = bias[r] + sum_k W[r][k] * x[t0+tloc][k][b]
__global__ __launch_bounds__(256, 2) void xproj_gemm(
    const float4* __restrict__ x, const float* __restrict__ W,
    const float* __restrict__ bih, const float* __restrict__ bhh,
    float* __restrict__ xp, int K4, int t0)
{
    __shared__ float wl[2][32 * PW];
    __shared__ float xl[2][32 * PX];
    const int tloc = blockIdx.x;
    const int bg   = blockIdx.y;
    const int rc   = blockIdx.z;
    const int tid  = threadIdx.x;
    const int K    = K4 * 4;
    const float4* xs = x + (size_t)(t0 + tloc) * K4 * 256;
    const int rbase = rc * 128;
    const int bbase = bg * 128;

    const int bcol = tid & 15;
    const int rrow = tid >> 4;
    const int b0 = 4 * bcol, r0 = 4 * rrow;

    const int wr  = tid >> 3;
    const int wkq = tid & 7;
    const int xb  = tid & 127;
    const int xk4 = tid >> 7;

    float acc[8][8];
    #pragma unroll
    for (int i = 0; i < 8; ++i)
        #pragma unroll
        for (int j = 0; j < 8; ++j) acc[i][j] = 0.f;

    const int nk = K4 >> 3;
    float4 wreg[4], xreg[4];

    #pragma unroll
    for (int j = 0; j < 4; ++j) {
        wreg[j] = *(const float4*)(W + (size_t)(rbase + wr + 32 * j) * K + wkq * 4);
        xreg[j] = xs[(size_t)(xk4 + 2 * j) * 256 + bbase + xb];
    }
    #pragma unroll
    for (int j = 0; j < 4; ++j) {
        #pragma unroll
        for (int i = 0; i < 4; ++i) {
            wl[0][(wkq * 4 + i) * PW + wr + 32 * j] = ((const float*)&wreg[j])[i];
            xl[0][((xk4 + 2 * j) * 4 + i) * PX + xb] = ((const float*)&xreg[j])[i];
        }
    }
    __syncthreads();

    for (int ro = 0; ro < nk; ++ro) {
        if (ro + 1 < nk) {
            const int k0 = (ro + 1) * 32;
            #pragma unroll
            for (int j = 0; j < 4; ++j) {
                wreg[j] = *(const float4*)(W + (size_t)(rbase + wr + 32 * j) * K + k0 + wkq * 4);
                xreg[j] = xs[(size_t)(k0 / 4 + xk4 + 2 * j) * 256 + bbase + xb];
            }
        }
        const float* wlb = wl[ro & 1];
        const float* xlb = xl[ro & 1];
        #pragma unroll 2
        for (int k = 0; k < 32; ++k) {
            const float4 w0 = *(const float4*)&wlb[k * PW + r0];
            const float4 w1 = *(const float4*)&wlb[k * PW + r0 + 64];
            const float4 v0 = *(const float4*)&xlb[k * PX + b0];
            const float4 v1 = *(const float4*)&xlb[k * PX + b0 + 64];
            const float wf[8] = {w0.x, w0.y, w0.z, w0.w, w1.x, w1.y, w1.z, w1.w};
            const float xf[8] = {v0.x, v0.y, v0.z, v0.w, v1.x, v1.y, v1.z, v1.w};
            #pragma unroll
            for (int i = 0; i < 8; ++i)
                #pragma unroll
                for (int j = 0; j < 8; ++j)
                    acc[i][j] += wf[i] * xf[j];
        }
        __syncthreads();
        if (ro + 1 < nk) {
            const int nb = (ro + 1) & 1;
            #pragma unroll
            for (int j = 0; j < 4; ++j) {
                #pragma unroll
                for (int i = 0; i < 4; ++i) {
                    wl[nb][(wkq * 4 + i) * PW + wr + 32 * j] = ((const float*)&wreg[j])[i];
                    xl[nb][((xk4 + 2 * j) * 4 + i) * PX + xb] = ((const float*)&xreg[j])[i];
                }
            }
            __syncthreads();
        }
    }

    #pragma unroll
    for (int ii = 0; ii < 8; ++ii) {
        const int rl = (ii < 4) ? (r0 + ii) : (r0 + 60 + ii);
        const int gr = rbase + rl;
        const float bias = bih[gr] + bhh[gr];
        float* o = xp + ((size_t)tloc * G + gr) * 256 + bbase;
        float4 u0 = {acc[ii][0] + bias, acc[ii][1] + bias, acc[ii][2] + bias, acc[ii][3] + bias};
        float4 u1 = {acc[ii][4] + bias, acc[ii][5] + bias, acc[ii][6] + bias, acc[ii][7] + bias};
        *(float4*)(o + b0) = u0;
        *(float4*)(o + b0 + 64) = u1;
    }
}

// One fused superstep per DISPATCH: the stream's dispatch boundary is the
// barrier (CP release/acquire handles cross-XCD visibility). No atomics, no
// sc1, no spins — all plain cached loads/stores; h broadcast-reads hit the
// local XCD L2. Superstep t: layer0 -> h0[t] (t<200), layer1 -> h1[t-1]
// (t>=1). h0/h1 are 2-slot ping-pongs [k4][b][4] float4-over-k; c in global.
// 256 blocks x 512 threads; wave owns 1 hid (wave-uniform -> scalar weight
// loads); lane = batch within the 64-batch group.
__global__ __launch_bounds__(512, 2) void lstm_step(
    const float* __restrict__ xp0, const float* __restrict__ Whh0,
    const float* __restrict__ Wih1, const float* __restrict__ Whh1,
    const float* __restrict__ bih1, const float* __restrict__ bhh1,
    float4* __restrict__ h0buf, float4* __restrict__ h1buf,
    float* __restrict__ cb0, float* __restrict__ cb1,
    int t, int tloc)
{
    __shared__ float4 hs[2][2048];   // 2 x 32 KB double buffer
    const int tid  = threadIdx.x;
    const int wv   = tid >> 6;       // 0..7
    const int lane = tid & 63;
    const int f    = blockIdx.x;     // 0..255
    const int jj   = f >> 3;
    const int bg   = jj & 3;                 // batch group (64 batches)
    const int hg   = (f & 7) + 8 * (jj >> 2);// hid group 0..63
    const int bG   = bg * 64 + lane;
    const int hid  = __builtin_amdgcn_readfirstlane(hg * 8 + wv);

    const float *w0[4], *wi[4], *w1[4];
    float bs1[4];
    #pragma unroll
    for (int q = 0; q < 4; ++q) {
        const int r = q * H + hid;
        w0[q] = Whh0 + (size_t)r * H;
        wi[q] = Wih1 + (size_t)r * H;
        w1[q] = Whh1 + (size_t)r * H;
        bs1[q] = bih1[r] + bhh1[r];
    }

    float a0[4], a1[4];
    if (t < T_ALL) {
        #pragma unroll
        for (int q = 0; q < 4; ++q)
            a0[q] = xp0[((size_t)tloc * G + q * H + hid) * 256 + bG];
    } else {
        #pragma unroll
        for (int q = 0; q < 4; ++q) a0[q] = 0.f;
    }
    #pragma unroll
    for (int q = 0; q < 4; ++q) a1[q] = bs1[q];

    if (t >= 1) {
        const float4* hin0 = h0buf + (size_t)((t - 1) & 1) * 32768;
        const float4* hin1 = h1buf + (size_t)((t - 2) & 1) * 32768;
        const int nro = (t >= 2) ? 8 : 4;
        #pragma unroll
        for (int s = 0; s < 4; ++s) {
            const int kk = wv + 8 * s;
            gl2lds16(hin0 + (size_t)kk * 256 + bG, &hs[0][kk * 64]);
        }
        __syncthreads();
        for (int ro = 0; ro < nro; ++ro) {
            if (ro + 1 < nro) {
                const float4* src = (ro + 1 < 4)
                    ? hin0 + (size_t)((ro + 1) * 32) * 256
                    : hin1 + (size_t)((ro - 3) * 32) * 256;
                #pragma unroll
                for (int s = 0; s < 4; ++s) {
                    const int kk = wv + 8 * s;
                    gl2lds16(src + (size_t)kk * 256 + bG, &hs[(ro + 1) & 1][kk * 64]);
                }
            }
            const float4* hb = hs[ro & 1];
            if (ro < 4) {
                const int kb = ro * 128;
                #pragma unroll 4
                for (int kk = 0; kk < 32; ++kk) {
                    const float4 v = hb[kk * 64 + lane];
                    const int ko = kb + kk * 4;
                    #pragma unroll
                    for (int q = 0; q < 4; ++q) {
                        const float4 w = *(const float4*)(w0[q] + ko);
                        a0[q] += w.x*v.x + w.y*v.y + w.z*v.z + w.w*v.w;
                        const float4 u = *(const float4*)(wi[q] + ko);
                        a1[q] += u.x*v.x + u.y*v.y + u.z*v.z + u.w*v.w;
                    }
                }
            } else {
                const int kb = (ro - 4) * 128;
                #pragma unroll 4
                for (int kk = 0; kk < 32; ++kk) {
                    const float4 v = hb[kk * 64 + lane];
                    const int ko = kb + kk * 4;
                    #pragma unroll
                    for (int q = 0; q < 4; ++q) {
                        const float4 w = *(const float4*)(w1[q] + ko);
                        a1[q] += w.x*v.x + w.y*v.y + w.z*v.z + w.w*v.w;
                    }
                }
            }
            __syncthreads();
        }
    }

    if (t < T_ALL) {
        float c0 = (t > 0) ? cb0[(size_t)hid * 256 + bG] : 0.f;
        float* hw = (float*)(h0buf + (size_t)(t & 1) * 32768);
        const float ig = sigf(a0[0]), fg = sigf(a0[1]);
        const float gg = tanhf(a0[2]), og = sigf(a0[3]);
        c0 = fg * c0 + ig * gg;
        hw[(((hid >> 2) * 256) + bG) * 4 + (hid & 3)] = og * tanhf(c0);
        cb0[(size_t)hid * 256 + bG] = c0;
    }
    if (t >= 1) {
        float c1 = (t > 1) ? cb1[(size_t)hid * 256 + bG] : 0.f;
        float* hw = (float*)(h1buf + (size_t)((t - 1) & 1) * 32768);
        const float ig = sigf(a1[0]), fg = sigf(a1[1]);
        const float gg = tanhf(a1[2]), og = sigf(a1[3]);
        c1 = fg * c1 + ig * gg;
        hw[(((hid >> 2) * 256) + bG) * 4 + (hid & 3)] = og * tanhf(c1);
        cb1[(size_t)hid * 256 + bG] = c1;
    }
}

// heads: base[k/4][b][4k] -> cls (256x40), bbox (256x2), 2 zero scalars
__global__ __launch_bounds__(64) void heads(
    const float4* __restrict__ base, const float4* __restrict__ clsW,
    const float* __restrict__ clsb, const float4* __restrict__ bbW,
    const float* __restrict__ bbb, float* __restrict__ out)
{
    const int b = blockIdx.x;
    const int j = threadIdx.x;
    if (j < 42) {
        const float4* w = (j < 40) ? (clsW + (size_t)j * 128) : (bbW + (size_t)(j - 40) * 128);
        float acc = 0.f;
        #pragma unroll 4
        for (int kk = 0; kk < 128; ++kk) {
            const float4 bv = base[(size_t)kk * 256 + b];
            const float4 wv = w[kk];
            acc += bv.x*wv.x + bv.y*wv.y + bv.z*wv.z + bv.w*wv.w;
        }
        if (j < 40) out[(size_t)b * 40 + j] = acc + clsb[j];
        else        out[10240 + (size_t)b * 2 + (j - 40)] = acc + bbb[j - 40];
    }
    if (b == 0 && (j == 62 || j == 63)) out[10752 + (j - 62)] = 0.f;
}

extern "C" void kernel_launch(void* const* d_in, const int* in_sizes, int n_in,
                              void* d_out, int out_size, void* d_ws, size_t ws_size,
                              hipStream_t stream) {
    const float* proposals = (const float*)d_in[2];
    const float* Wih0 = (const float*)d_in[4];
    const float* Whh0 = (const float*)d_in[5];
    const float* bih0 = (const float*)d_in[6];
    const float* bhh0 = (const float*)d_in[7];
    const float* Wih1 = (const float*)d_in[8];
    const float* Whh1 = (const float*)d_in[9];
    const float* bih1 = (const float*)d_in[10];
    const float* bhh1 = (const float*)d_in[11];
    const float* clsW = (const float*)d_in[12];
    const float* clsb = (const float*)d_in[13];
    const float* bbW  = (const float*)d_in[14];
    const float* bbb  = (const float*)d_in[15];

    char* ws = (char*)d_ws;
    const size_t XT_B = 200ull * 32 * 256 * 16;   // 26,214,400
    const size_t HB_B = 2ull * 32768 * 16;        // 1,048,576 per layer ping-pong
    const size_t C_B  = 512ull * 256 * 4;         // 524,288 per layer
    const size_t XP_T = (size_t)G * 256 * 4;      // 2,097,152 per layer0 step
    const size_t base = XT_B + 2 * HB_B + 2 * C_B;

    long long avail = (long long)ws_size - (long long)base;
    int TC = avail > 0 ? (int)(avail / (long long)XP_T) : 1;
    if (TC > T_ALL) TC = T_ALL;
    if (TC < 1) TC = 1;

    float4* xT  = (float4*)ws;
    float4* h0b = (float4*)(ws + XT_B);
    float4* h1b = (float4*)(ws + XT_B + HB_B);
    float*  cb0 = (float*)(ws + XT_B + 2 * HB_B);
    float*  cb1 = (float*)(ws + XT_B + 2 * HB_B + C_B);
    float*  xp0 = (float*)(ws + base);

    transpose_x<<<200, 256, 0, stream>>>((const float4*)proposals, xT);

    for (int t0 = 0; t0 < T_ALL + 1; t0 += TC) {
        const int t1 = (t0 + TC < T_ALL + 1) ? (t0 + TC) : (T_ALL + 1);
        const int lim = (t1 < T_ALL) ? t1 : T_ALL;
        const int len0 = lim - t0;                 // layer0 steps needing xp
        if (len0 > 0)
            xproj_gemm<<<dim3(len0, 2, 16), 256, 0, stream>>>(xT, Wih0, bih0, bhh0,
                                                              xp0, 32, t0);
        for (int t = t0; t < t1; ++t)
            lstm_step<<<256, 512, 0, stream>>>(xp0, Whh0, Wih1, Whh1, bih1, bhh1,
                                               h0b, h1b, cb0, cb1,
                                               t, (t < T_ALL) ? (t - t0) : 0);
    }

    // base_feat = h1 slot (199 & 1) = 1
    heads<<<256, 64, 0, stream>>>((const float4*)(h1b + 32768), (const float4*)clsW,
                                  clsb, (const float4*)bbW, bbb, (float*)d_out);
}